// Round 1
// baseline (136.425 us; speedup 1.0000x reference)
//
#include <hip/hip_runtime.h>

// MHA: B=4, T=1024, D=1024, H=16, HD=64. Causal mask, interleaved RoPE.
// Strategy: bf16 MFMA (16x16x32) for all GEMMs, fp32 accumulate.
// ws layout: xb(8M) | wq/wk/wv/wo bf16 (2M each) | qbuf(8M) | kbuf(8M) | vt(8M) | ctx(8M) | cos/sin tables

#define T_SEQ 1024
#define NH    16
#define HDIM  64
#define DM    1024
#define MTOK  4096   // B*T

typedef __attribute__((ext_vector_type(8))) short short8;
typedef __attribute__((ext_vector_type(4))) float f32x4;
typedef unsigned short u16;

__device__ __forceinline__ u16 f2bf(float f) {
  unsigned int u = __builtin_bit_cast(unsigned int, f);
  u += 0x7fffu + ((u >> 16) & 1u);
  return (u16)(u >> 16);
}

// async global->LDS, 16B per lane. LDS dest must be wave-uniform base + lane*16.
__device__ __forceinline__ void gll16(const void* g, void* l) {
  __builtin_amdgcn_global_load_lds(
      (const __attribute__((address_space(1))) unsigned int*)(unsigned long long)(g),
      (__attribute__((address_space(3))) unsigned int*)(unsigned int)(unsigned long long)(l),
      16, 0, 0);
}

// ---------------- converts ----------------
__global__ void cvt4(const float* __restrict__ in, u16* __restrict__ out) {
  int i = blockIdx.x * 256 + threadIdx.x;
  float4 f = ((const float4*)in)[i];
  unsigned long long pk = (unsigned long long)f2bf(f.x)
                        | ((unsigned long long)f2bf(f.y) << 16)
                        | ((unsigned long long)f2bf(f.z) << 32)
                        | ((unsigned long long)f2bf(f.w) << 48);
  ((unsigned long long*)out)[i] = pk;
}

__global__ void cvtW(const float* __restrict__ w0, const float* __restrict__ w1,
                     const float* __restrict__ w2, const float* __restrict__ w3,
                     u16* __restrict__ out) {
  const float* src = blockIdx.y == 0 ? w0 : blockIdx.y == 1 ? w1 : blockIdx.y == 2 ? w2 : w3;
  u16* dst = out + (size_t)blockIdx.y * (DM * DM);
  int i = blockIdx.x * 256 + threadIdx.x;
  float4 f = ((const float4*)src)[i];
  unsigned long long pk = (unsigned long long)f2bf(f.x)
                        | ((unsigned long long)f2bf(f.y) << 16)
                        | ((unsigned long long)f2bf(f.z) << 32)
                        | ((unsigned long long)f2bf(f.w) << 48);
  ((unsigned long long*)dst)[i] = pk;
}

__global__ void rope_tab(float* __restrict__ c, float* __restrict__ s) {
  int idx = blockIdx.x * 256 + threadIdx.x;  // T*32
  int t = idx >> 5, i = idx & 31;
  float inv = powf(10000.f, -(float)i * (1.0f / 32.0f));
  float f = (float)t * inv;
  c[idx] = cosf(f);
  s[idx] = sinf(f);
}

// ---------------- GEMM mainloop: C[128x128] tile, A:[M][K] bf16, Bw:[N][K] bf16 (B^T input) ----
__device__ __forceinline__ void gemm_mainloop(
    const u16* __restrict__ A, const u16* __restrict__ Bw,
    int m0, int n0, int K, u16* Asm, u16* Bsm, f32x4 acc[4][4]) {
  const int tid = threadIdx.x, lane = tid & 63, wave = tid >> 6;
  const int wr = wave >> 1, wc = wave & 1;
  for (int k0 = 0; k0 < K; k0 += 32) {
#pragma unroll
    for (int c = 0; c < 2; ++c) {
      gll16(&A[(size_t)(m0 + c * 64 + (tid >> 2)) * K + k0 + (tid & 3) * 8], &Asm[c * 2048 + tid * 8]);
      gll16(&Bw[(size_t)(n0 + c * 64 + (tid >> 2)) * K + k0 + (tid & 3) * 8], &Bsm[c * 2048 + tid * 8]);
    }
    __syncthreads();
    short8 af[4], bf[4];
#pragma unroll
    for (int i = 0; i < 4; ++i) {
      af[i] = *(const short8*)&Asm[(wr * 64 + i * 16 + (lane & 15)) * 32 + ((lane >> 4) * 8)];
      bf[i] = *(const short8*)&Bsm[(wc * 64 + i * 16 + (lane & 15)) * 32 + ((lane >> 4) * 8)];
    }
#pragma unroll
    for (int i = 0; i < 4; ++i)
#pragma unroll
      for (int j = 0; j < 4; ++j)
        acc[i][j] = __builtin_amdgcn_mfma_f32_16x16x32_bf16(af[i], bf[j], acc[i][j], 0, 0, 0);
    __syncthreads();
  }
}

// ---------------- fused QKV projection + bias + RoPE + layout ----------------
__global__ __launch_bounds__(256) void qkv_kernel(
    const u16* __restrict__ xb,
    const u16* __restrict__ Wqb, const u16* __restrict__ Wkb, const u16* __restrict__ Wvb,
    const float* __restrict__ bq, const float* __restrict__ bk, const float* __restrict__ bv,
    const float* __restrict__ ctab, const float* __restrict__ stab,
    u16* __restrict__ qbuf, u16* __restrict__ kbuf, u16* __restrict__ vt) {
  __shared__ __align__(16) u16 Asm[128 * 32];
  __shared__ __align__(16) u16 Bsm[128 * 32];
  const int mode = blockIdx.z;
  const u16* Bw = mode == 0 ? Wqb : (mode == 1 ? Wkb : Wvb);
  const float* bias = mode == 0 ? bq : (mode == 1 ? bk : bv);
  const int m0 = blockIdx.y * 128, n0 = blockIdx.x * 128;
  f32x4 acc[4][4];
#pragma unroll
  for (int i = 0; i < 4; ++i)
#pragma unroll
    for (int j = 0; j < 4; ++j)
#pragma unroll
      for (int r = 0; r < 4; ++r) acc[i][j][r] = 0.f;
  gemm_mainloop(xb, Bw, m0, n0, DM, Asm, Bsm, acc);

  const int lane = threadIdx.x & 63, wave = threadIdx.x >> 6;
  const int wr = wave >> 1, wc = wave & 1;
#pragma unroll
  for (int i = 0; i < 4; ++i) {
#pragma unroll
    for (int j = 0; j < 4; ++j) {
      const int e = n0 + wc * 64 + j * 16 + (lane & 15);
      const float bval = bias[e];
      const int h = e >> 6, hd = e & 63;
#pragma unroll
      for (int r = 0; r < 4; ++r) {
        const int m = m0 + wr * 64 + i * 16 + ((lane >> 4) * 4) + r;
        const int b = m >> 10, t = m & 1023;
        float v = acc[i][j][r] + bval;
        if (mode < 2) {
          float p = __shfl_xor(v, 1);  // partner within the (even,odd) pair
          const int fi = hd >> 1;
          const float cc = ctab[t * 32 + fi], ss = stab[t * 32 + fi];
          v = (hd & 1) ? (v * cc + p * ss) : (v * cc - p * ss);
          u16* dst = mode == 0 ? qbuf : kbuf;
          dst[(((size_t)(b * NH + h) * T_SEQ + t) << 6) + hd] = f2bf(v);
        } else {
          vt[(((size_t)(b * NH + h) * HDIM + hd) << 10) + t] = f2bf(v);
        }
      }
    }
  }
}

// ---------------- flash attention: 1 block = (b,h, 64 q-rows), 4 waves x 16 rows ----------------
__global__ __launch_bounds__(256) void attn_kernel(
    const u16* __restrict__ qbuf, const u16* __restrict__ kbuf,
    const u16* __restrict__ vtb, u16* __restrict__ ctx) {
  __shared__ __align__(16) u16 Ksm[64 * 64];   // [kv][hd]
  __shared__ __align__(16) u16 Vsm[64 * 64];   // [hd][kv]  (V^T tile)
  __shared__ __align__(16) u16 Psm[4][16 * 64];
  const int bh = blockIdx.x, qt = blockIdx.y;
  const int b = bh >> 4, h = bh & 15;
  const int tid = threadIdx.x, lane = tid & 63, wave = tid >> 6;
  const u16* Qp = qbuf + (size_t)bh * T_SEQ * HDIM;
  const u16* Kp = kbuf + (size_t)bh * T_SEQ * HDIM;
  const u16* Vp = vtb + (size_t)bh * HDIM * T_SEQ;
  const int q0 = qt * 64;
  const int qrow = q0 + wave * 16 + (lane & 15);
  const short8 qf0 = *(const short8*)&Qp[qrow * 64 + ((lane >> 4) * 8)];
  const short8 qf1 = *(const short8*)&Qp[qrow * 64 + 32 + ((lane >> 4) * 8)];

  f32x4 acc_o[4];
  float m_r[4], l_r[4];
#pragma unroll
  for (int i = 0; i < 4; ++i) {
#pragma unroll
    for (int r = 0; r < 4; ++r) acc_o[i][r] = 0.f;
    m_r[i] = -__builtin_inff();
    l_r[i] = 0.f;
  }

  const int nkv = qt + 1;
  for (int kvt = 0; kvt < nkv; ++kvt) {
#pragma unroll
    for (int c = 0; c < 2; ++c) {
      gll16(&Kp[kvt * 4096 + c * 2048 + tid * 8], &Ksm[c * 2048 + tid * 8]);
      gll16(&Vp[(c * 32 + (tid >> 3)) * T_SEQ + kvt * 64 + (tid & 7) * 8], &Vsm[c * 2048 + tid * 8]);
    }
    __syncthreads();

    // S = Q K^T (16x64 per wave)
    f32x4 sacc[4];
#pragma unroll
    for (int cb = 0; cb < 4; ++cb)
#pragma unroll
      for (int r = 0; r < 4; ++r) sacc[cb][r] = 0.f;
#pragma unroll
    for (int cb = 0; cb < 4; ++cb) {
      short8 kf0 = *(const short8*)&Ksm[(cb * 16 + (lane & 15)) * 64 + ((lane >> 4) * 8)];
      short8 kf1 = *(const short8*)&Ksm[(cb * 16 + (lane & 15)) * 64 + 32 + ((lane >> 4) * 8)];
      sacc[cb] = __builtin_amdgcn_mfma_f32_16x16x32_bf16(qf0, kf0, sacc[cb], 0, 0, 0);
      sacc[cb] = __builtin_amdgcn_mfma_f32_16x16x32_bf16(qf1, kf1, sacc[cb], 0, 0, 0);
    }
    // scale + causal mask
    const int trow_base = q0 + wave * 16 + ((lane >> 4) * 4);
#pragma unroll
    for (int cb = 0; cb < 4; ++cb) {
      const int scol = kvt * 64 + cb * 16 + (lane & 15);
#pragma unroll
      for (int r = 0; r < 4; ++r) {
        float sv = sacc[cb][r] * 0.125f;
        sacc[cb][r] = (scol > trow_base + r) ? -__builtin_inff() : sv;
      }
    }
    // online softmax (rows live across 16 lanes x 4 col-blocks)
    float mt[4];
#pragma unroll
    for (int r = 0; r < 4; ++r)
      mt[r] = fmaxf(fmaxf(sacc[0][r], sacc[1][r]), fmaxf(sacc[2][r], sacc[3][r]));
#pragma unroll
    for (int off = 1; off < 16; off <<= 1)
#pragma unroll
      for (int r = 0; r < 4; ++r) mt[r] = fmaxf(mt[r], __shfl_xor(mt[r], off));
    float sf[4], lt[4];
#pragma unroll
    for (int r = 0; r < 4; ++r) {
      const float mn = fmaxf(m_r[r], mt[r]);
      sf[r] = __expf(m_r[r] - mn);
      m_r[r] = mn;
      lt[r] = 0.f;
    }
#pragma unroll
    for (int cb = 0; cb < 4; ++cb)
#pragma unroll
      for (int r = 0; r < 4; ++r) {
        const float p = __expf(sacc[cb][r] - m_r[r]);
        sacc[cb][r] = p;
        lt[r] += p;
      }
#pragma unroll
    for (int off = 1; off < 16; off <<= 1)
#pragma unroll
      for (int r = 0; r < 4; ++r) lt[r] += __shfl_xor(lt[r], off);
#pragma unroll
    for (int r = 0; r < 4; ++r) l_r[r] = l_r[r] * sf[r] + lt[r];
#pragma unroll
    for (int hb = 0; hb < 4; ++hb)
#pragma unroll
      for (int r = 0; r < 4; ++r) acc_o[hb][r] *= sf[r];

    // P (C-layout) -> LDS -> A-layout
    u16* Pp = &Psm[wave][0];
#pragma unroll
    for (int cb = 0; cb < 4; ++cb)
#pragma unroll
      for (int r = 0; r < 4; ++r)
        Pp[(((lane >> 4) * 4) + r) * 64 + cb * 16 + (lane & 15)] = f2bf(sacc[cb][r]);

    // O += P V
#pragma unroll
    for (int kc = 0; kc < 2; ++kc) {
      short8 pf = *(const short8*)&Pp[(lane & 15) * 64 + kc * 32 + ((lane >> 4) * 8)];
#pragma unroll
      for (int hb = 0; hb < 4; ++hb) {
        short8 vf = *(const short8*)&Vsm[(hb * 16 + (lane & 15)) * 64 + kc * 32 + ((lane >> 4) * 8)];
        acc_o[hb] = __builtin_amdgcn_mfma_f32_16x16x32_bf16(pf, vf, acc_o[hb], 0, 0, 0);
      }
    }
    __syncthreads();
  }

  // epilogue: ctx[b][t][h][hd] bf16
#pragma unroll
  for (int hb = 0; hb < 4; ++hb) {
    const int hd = hb * 16 + (lane & 15);
#pragma unroll
    for (int r = 0; r < 4; ++r) {
      const int t = q0 + wave * 16 + ((lane >> 4) * 4) + r;
      const float v = acc_o[hb][r] / l_r[r];
      ctx[((size_t)(b * T_SEQ + t) * NH + h) * HDIM + hd] = f2bf(v);
    }
  }
}

// ---------------- output projection -> fp32 d_out ----------------
__global__ __launch_bounds__(256) void oproj_kernel(
    const u16* __restrict__ ctx, const u16* __restrict__ Wob,
    const float* __restrict__ bo, float* __restrict__ out) {
  __shared__ __align__(16) u16 Asm[128 * 32];
  __shared__ __align__(16) u16 Bsm[128 * 32];
  const int m0 = blockIdx.y * 128, n0 = blockIdx.x * 128;
  f32x4 acc[4][4];
#pragma unroll
  for (int i = 0; i < 4; ++i)
#pragma unroll
    for (int j = 0; j < 4; ++j)
#pragma unroll
      for (int r = 0; r < 4; ++r) acc[i][j][r] = 0.f;
  gemm_mainloop(ctx, Wob, m0, n0, DM, Asm, Bsm, acc);
  const int lane = threadIdx.x & 63, wave = threadIdx.x >> 6;
  const int wr = wave >> 1, wc = wave & 1;
#pragma unroll
  for (int i = 0; i < 4; ++i)
#pragma unroll
    for (int j = 0; j < 4; ++j) {
      const int e = n0 + wc * 64 + j * 16 + (lane & 15);
      const float bval = bo[e];
#pragma unroll
      for (int r = 0; r < 4; ++r) {
        const int m = m0 + wr * 64 + i * 16 + ((lane >> 4) * 4) + r;
        out[(size_t)m * DM + e] = acc[i][j][r] + bval;
      }
    }
}

extern "C" void kernel_launch(void* const* d_in, const int* in_sizes, int n_in,
                              void* d_out, int out_size, void* d_ws, size_t ws_size,
                              hipStream_t stream) {
  const float* x  = (const float*)d_in[0];
  const float* Wq = (const float*)d_in[1];
  const float* bq = (const float*)d_in[2];
  const float* Wk = (const float*)d_in[3];
  const float* bk = (const float*)d_in[4];
  const float* Wv = (const float*)d_in[5];
  const float* bv = (const float*)d_in[6];
  const float* Wo = (const float*)d_in[7];
  const float* bo = (const float*)d_in[8];

  char* w = (char*)d_ws;
  u16* xb   = (u16*)(w);
  u16* wqb  = (u16*)(w + (8ull << 20));
  u16* wkb  = (u16*)(w + (10ull << 20));
  u16* wvb  = (u16*)(w + (12ull << 20));
  u16* wob  = (u16*)(w + (14ull << 20));
  u16* qb   = (u16*)(w + (16ull << 20));
  u16* kb   = (u16*)(w + (24ull << 20));
  u16* vtb  = (u16*)(w + (32ull << 20));
  u16* ctxb = (u16*)(w + (40ull << 20));
  float* ctab = (float*)(w + (48ull << 20));
  float* stab = ctab + T_SEQ * 32;

  cvt4<<<dim3((MTOK * DM) / 4 / 256), 256, 0, stream>>>(x, xb);
  cvtW<<<dim3((DM * DM) / 4 / 256, 4), 256, 0, stream>>>(Wq, Wk, Wv, Wo, wqb);
  rope_tab<<<dim3((T_SEQ * 32) / 256), 256, 0, stream>>>(ctab, stab);
  qkv_kernel<<<dim3(DM / 128, MTOK / 128, 3), 256, 0, stream>>>(
      xb, wqb, wkb, wvb, bq, bk, bv, ctab, stab, qb, kb, vtb);
  attn_kernel<<<dim3(64, T_SEQ / 64), 256, 0, stream>>>(qb, kb, vtb, ctxb);
  oproj_kernel<<<dim3(DM / 128, MTOK / 128), 256, 0, stream>>>(ctxb, wob, bo, (float*)d_out);
}

// Round 2
// 123.365 us; speedup vs baseline: 1.1059x; 1.1059x over previous
//
#include <hip/hip_runtime.h>

// MHA: B=4, T=1024, D=1024, H=16, HD=64. Causal mask, interleaved RoPE.
// bf16 MFMA (16x16x32) everywhere, fp32 accumulate.
// R2: attn rewrite — XOR-swizzled LDS (K/V via pre-swizzled global src for
// global_load_lds; P swizzled both sides), double-buffered K/V, uniform
// work pairing (q-tiles qt and 15-qt per block => 17 KV tiles/block).

#define T_SEQ 1024
#define NH    16
#define HDIM  64
#define DM    1024
#define MTOK  4096   // B*T

typedef __attribute__((ext_vector_type(8))) short short8;
typedef __attribute__((ext_vector_type(4))) float f32x4;
typedef unsigned short u16;

__device__ __forceinline__ u16 f2bf(float f) {
  unsigned int u = __builtin_bit_cast(unsigned int, f);
  u += 0x7fffu + ((u >> 16) & 1u);
  return (u16)(u >> 16);
}

// async global->LDS, 16B per lane. LDS dest must be wave-uniform base + lane*16.
__device__ __forceinline__ void gll16(const void* g, void* l) {
  __builtin_amdgcn_global_load_lds(
      (const __attribute__((address_space(1))) unsigned int*)(unsigned long long)(g),
      (__attribute__((address_space(3))) unsigned int*)(unsigned int)(unsigned long long)(l),
      16, 0, 0);
}

// ---------------- converts ----------------
__global__ void cvt4(const float* __restrict__ in, u16* __restrict__ out) {
  int i = blockIdx.x * 256 + threadIdx.x;
  float4 f = ((const float4*)in)[i];
  unsigned long long pk = (unsigned long long)f2bf(f.x)
                        | ((unsigned long long)f2bf(f.y) << 16)
                        | ((unsigned long long)f2bf(f.z) << 32)
                        | ((unsigned long long)f2bf(f.w) << 48);
  ((unsigned long long*)out)[i] = pk;
}

__global__ void cvtW(const float* __restrict__ w0, const float* __restrict__ w1,
                     const float* __restrict__ w2, const float* __restrict__ w3,
                     u16* __restrict__ out) {
  const float* src = blockIdx.y == 0 ? w0 : blockIdx.y == 1 ? w1 : blockIdx.y == 2 ? w2 : w3;
  u16* dst = out + (size_t)blockIdx.y * (DM * DM);
  int i = blockIdx.x * 256 + threadIdx.x;
  float4 f = ((const float4*)src)[i];
  unsigned long long pk = (unsigned long long)f2bf(f.x)
                        | ((unsigned long long)f2bf(f.y) << 16)
                        | ((unsigned long long)f2bf(f.z) << 32)
                        | ((unsigned long long)f2bf(f.w) << 48);
  ((unsigned long long*)dst)[i] = pk;
}

__global__ void rope_tab(float* __restrict__ c, float* __restrict__ s) {
  int idx = blockIdx.x * 256 + threadIdx.x;  // T*32
  int t = idx >> 5, i = idx & 31;
  float inv = powf(10000.f, -(float)i * (1.0f / 32.0f));
  float f = (float)t * inv;
  c[idx] = cosf(f);
  s[idx] = sinf(f);
}

// ---------------- GEMM mainloop: C[128x128] tile, A:[M][K] bf16, Bw:[N][K] bf16 (B^T input) ----
__device__ __forceinline__ void gemm_mainloop(
    const u16* __restrict__ A, const u16* __restrict__ Bw,
    int m0, int n0, int K, u16* Asm, u16* Bsm, f32x4 acc[4][4]) {
  const int tid = threadIdx.x, lane = tid & 63, wave = tid >> 6;
  const int wr = wave >> 1, wc = wave & 1;
  for (int k0 = 0; k0 < K; k0 += 32) {
#pragma unroll
    for (int c = 0; c < 2; ++c) {
      gll16(&A[(size_t)(m0 + c * 64 + (tid >> 2)) * K + k0 + (tid & 3) * 8], &Asm[c * 2048 + tid * 8]);
      gll16(&Bw[(size_t)(n0 + c * 64 + (tid >> 2)) * K + k0 + (tid & 3) * 8], &Bsm[c * 2048 + tid * 8]);
    }
    __syncthreads();
    short8 af[4], bf[4];
#pragma unroll
    for (int i = 0; i < 4; ++i) {
      af[i] = *(const short8*)&Asm[(wr * 64 + i * 16 + (lane & 15)) * 32 + ((lane >> 4) * 8)];
      bf[i] = *(const short8*)&Bsm[(wc * 64 + i * 16 + (lane & 15)) * 32 + ((lane >> 4) * 8)];
    }
#pragma unroll
    for (int i = 0; i < 4; ++i)
#pragma unroll
      for (int j = 0; j < 4; ++j)
        acc[i][j] = __builtin_amdgcn_mfma_f32_16x16x32_bf16(af[i], bf[j], acc[i][j], 0, 0, 0);
    __syncthreads();
  }
}

// ---------------- fused QKV projection + bias + RoPE + layout ----------------
__global__ __launch_bounds__(256) void qkv_kernel(
    const u16* __restrict__ xb,
    const u16* __restrict__ Wqb, const u16* __restrict__ Wkb, const u16* __restrict__ Wvb,
    const float* __restrict__ bq, const float* __restrict__ bk, const float* __restrict__ bv,
    const float* __restrict__ ctab, const float* __restrict__ stab,
    u16* __restrict__ qbuf, u16* __restrict__ kbuf, u16* __restrict__ vt) {
  __shared__ __align__(16) u16 Asm[128 * 32];
  __shared__ __align__(16) u16 Bsm[128 * 32];
  const int mode = blockIdx.z;
  const u16* Bw = mode == 0 ? Wqb : (mode == 1 ? Wkb : Wvb);
  const float* bias = mode == 0 ? bq : (mode == 1 ? bk : bv);
  const int m0 = blockIdx.y * 128, n0 = blockIdx.x * 128;
  f32x4 acc[4][4];
#pragma unroll
  for (int i = 0; i < 4; ++i)
#pragma unroll
    for (int j = 0; j < 4; ++j)
#pragma unroll
      for (int r = 0; r < 4; ++r) acc[i][j][r] = 0.f;
  gemm_mainloop(xb, Bw, m0, n0, DM, Asm, Bsm, acc);

  const int lane = threadIdx.x & 63, wave = threadIdx.x >> 6;
  const int wr = wave >> 1, wc = wave & 1;
#pragma unroll
  for (int i = 0; i < 4; ++i) {
#pragma unroll
    for (int j = 0; j < 4; ++j) {
      const int e = n0 + wc * 64 + j * 16 + (lane & 15);
      const float bval = bias[e];
      const int h = e >> 6, hd = e & 63;
#pragma unroll
      for (int r = 0; r < 4; ++r) {
        const int m = m0 + wr * 64 + i * 16 + ((lane >> 4) * 4) + r;
        const int b = m >> 10, t = m & 1023;
        float v = acc[i][j][r] + bval;
        if (mode < 2) {
          float p = __shfl_xor(v, 1);  // partner within the (even,odd) pair
          const int fi = hd >> 1;
          const float cc = ctab[t * 32 + fi], ss = stab[t * 32 + fi];
          v = (hd & 1) ? (v * cc + p * ss) : (v * cc - p * ss);
          u16* dst = mode == 0 ? qbuf : kbuf;
          dst[(((size_t)(b * NH + h) * T_SEQ + t) << 6) + hd] = f2bf(v);
        } else {
          vt[(((size_t)(b * NH + h) * HDIM + hd) << 10) + t] = f2bf(v);
        }
      }
    }
  }
}

// ---------------- flash attention ----------------
// Block = (b,h) x {q-tile qt, q-tile 15-qt}: uniform 17 KV tiles per block.
// 4 waves x 16 q-rows. K/V double-buffered + XOR-swizzled LDS.
// Swizzle: within a 128B row, 16B-chunk index ^= (row&7). For gll16 (linear
// LDS dest) the swizzle is applied to the per-lane GLOBAL source address;
// reads apply the same XOR => involution (both-sides rule).
__global__ __launch_bounds__(256) void attn_kernel(
    const u16* __restrict__ qbuf, const u16* __restrict__ kbuf,
    const u16* __restrict__ vtb, u16* __restrict__ ctx) {
  __shared__ __align__(16) u16 Ks[2][64 * 64];   // [kv][hd] swizzled
  __shared__ __align__(16) u16 Vs[2][64 * 64];   // [hd][kv] swizzled (V^T tile)
  __shared__ __align__(16) u16 Psm[4][16 * 64];  // per-wave P, swizzled
  const int bh = blockIdx.x;
  const int b = bh >> 4, h = bh & 15;
  const int tid = threadIdx.x, lane = tid & 63, wave = tid >> 6;
  const u16* Qp = qbuf + (size_t)bh * T_SEQ * HDIM;
  const u16* Kp = kbuf + (size_t)bh * T_SEQ * HDIM;
  const u16* Vp = vtb + (size_t)bh * HDIM * T_SEQ;
  u16* Pw = &Psm[wave][0];

  const int srow = tid >> 3;                    // staging row (0..31, +32 for c=1)
  const int schx = ((tid & 7) ^ (srow & 7)) * 8; // pre-swizzled chunk (u16 offset)
  const int lx = lane & 7;                      // row&7 for all read rows below

#define STG(kvt, bb)                                                            \
  do {                                                                          \
    _Pragma("unroll") for (int c = 0; c < 2; ++c) {                             \
      const int rr = c * 32 + srow;                                             \
      gll16(&Kp[(kvt) * 4096 + rr * 64 + schx], &Ks[bb][c * 2048 + tid * 8]);   \
      gll16(&Vp[(size_t)rr * T_SEQ + (kvt) * 64 + schx], &Vs[bb][c * 2048 + tid * 8]); \
    }                                                                           \
  } while (0)

  for (int phase = 0; phase < 2; ++phase) {
    const int qt = phase ? (15 - (int)blockIdx.y) : (int)blockIdx.y;
    const int q0 = qt * 64;
    const int nkv = qt + 1;
    const int qrow = q0 + wave * 16 + (lane & 15);
    const short8 qf0 = *(const short8*)&Qp[qrow * 64 + ((lane >> 4) * 8)];
    const short8 qf1 = *(const short8*)&Qp[qrow * 64 + 32 + ((lane >> 4) * 8)];

    f32x4 acc_o[4];
    float m_r[4], l_r[4];
#pragma unroll
    for (int i = 0; i < 4; ++i) {
#pragma unroll
      for (int r = 0; r < 4; ++r) acc_o[i][r] = 0.f;
      m_r[i] = -__builtin_inff();
      l_r[i] = 0.f;
    }

    __syncthreads();   // previous phase's readers done before restaging buf0
    STG(0, 0);
    int cur = 0;

    for (int kvt = 0; kvt < nkv; ++kvt) {
      __syncthreads();                       // buf[cur] staged (vmcnt drained)
      if (kvt + 1 < nkv) STG(kvt + 1, cur ^ 1);

      // S = Q K^T (16x64 per wave)
      f32x4 sacc[4];
#pragma unroll
      for (int cb = 0; cb < 4; ++cb) {
#pragma unroll
        for (int r = 0; r < 4; ++r) sacc[cb][r] = 0.f;
        const int krow = cb * 16 + (lane & 15);
        const short8 kf0 = *(const short8*)&Ks[cur][krow * 64 + (((lane >> 4) ^ lx) * 8)];
        const short8 kf1 = *(const short8*)&Ks[cur][krow * 64 + (((4 + (lane >> 4)) ^ lx) * 8)];
        sacc[cb] = __builtin_amdgcn_mfma_f32_16x16x32_bf16(qf0, kf0, sacc[cb], 0, 0, 0);
        sacc[cb] = __builtin_amdgcn_mfma_f32_16x16x32_bf16(qf1, kf1, sacc[cb], 0, 0, 0);
      }
      // scale + causal mask
      const int trow_base = q0 + wave * 16 + ((lane >> 4) * 4);
#pragma unroll
      for (int cb = 0; cb < 4; ++cb) {
        const int scol = kvt * 64 + cb * 16 + (lane & 15);
#pragma unroll
        for (int r = 0; r < 4; ++r) {
          float sv = sacc[cb][r] * 0.125f;
          sacc[cb][r] = (scol > trow_base + r) ? -__builtin_inff() : sv;
        }
      }
      // online softmax (rows live across 16 lanes x 4 col-blocks)
      float mt[4];
#pragma unroll
      for (int r = 0; r < 4; ++r)
        mt[r] = fmaxf(fmaxf(sacc[0][r], sacc[1][r]), fmaxf(sacc[2][r], sacc[3][r]));
#pragma unroll
      for (int off = 1; off < 16; off <<= 1)
#pragma unroll
        for (int r = 0; r < 4; ++r) mt[r] = fmaxf(mt[r], __shfl_xor(mt[r], off));
      float sf[4], lt[4];
#pragma unroll
      for (int r = 0; r < 4; ++r) {
        const float mn = fmaxf(m_r[r], mt[r]);
        sf[r] = __expf(m_r[r] - mn);
        m_r[r] = mn;
        lt[r] = 0.f;
      }
#pragma unroll
      for (int cb = 0; cb < 4; ++cb)
#pragma unroll
        for (int r = 0; r < 4; ++r) {
          const float p = __expf(sacc[cb][r] - m_r[r]);
          sacc[cb][r] = p;
          lt[r] += p;
        }
#pragma unroll
      for (int off = 1; off < 16; off <<= 1)
#pragma unroll
        for (int r = 0; r < 4; ++r) lt[r] += __shfl_xor(lt[r], off);
#pragma unroll
      for (int r = 0; r < 4; ++r) l_r[r] = l_r[r] * sf[r] + lt[r];
#pragma unroll
      for (int hb = 0; hb < 4; ++hb)
#pragma unroll
        for (int r = 0; r < 4; ++r) acc_o[hb][r] *= sf[r];

      // P (C-layout) -> LDS (swizzled) -> A-layout
#pragma unroll
      for (int cb = 0; cb < 4; ++cb)
#pragma unroll
        for (int r = 0; r < 4; ++r) {
          const int prow = (lane >> 4) * 4 + r;
          Pw[prow * 64 + ((cb * 16 + (lane & 15)) ^ ((prow & 7) << 3))] = f2bf(sacc[cb][r]);
        }

      // O += P V
      const int prr = lane & 15;
#pragma unroll
      for (int kc = 0; kc < 2; ++kc) {
        const short8 pf = *(const short8*)&Pw[prr * 64 + (((kc * 4 + (lane >> 4)) ^ lx) * 8)];
#pragma unroll
        for (int hb = 0; hb < 4; ++hb) {
          const int vrow = hb * 16 + (lane & 15);
          const short8 vf = *(const short8*)&Vs[cur][vrow * 64 + (((kc * 4 + (lane >> 4)) ^ lx) * 8)];
          acc_o[hb] = __builtin_amdgcn_mfma_f32_16x16x32_bf16(pf, vf, acc_o[hb], 0, 0, 0);
        }
      }
      cur ^= 1;
    }

    // epilogue: ctx[b][t][h][hd] bf16
#pragma unroll
    for (int hb = 0; hb < 4; ++hb) {
      const int hd = hb * 16 + (lane & 15);
#pragma unroll
      for (int r = 0; r < 4; ++r) {
        const int t = q0 + wave * 16 + ((lane >> 4) * 4) + r;
        const float v = acc_o[hb][r] / l_r[r];
        ctx[((size_t)(b * T_SEQ + t) * NH + h) * HDIM + hd] = f2bf(v);
      }
    }
  }
#undef STG
}

// ---------------- output projection -> fp32 d_out ----------------
__global__ __launch_bounds__(256) void oproj_kernel(
    const u16* __restrict__ ctx, const u16* __restrict__ Wob,
    const float* __restrict__ bo, float* __restrict__ out) {
  __shared__ __align__(16) u16 Asm[128 * 32];
  __shared__ __align__(16) u16 Bsm[128 * 32];
  const int m0 = blockIdx.y * 128, n0 = blockIdx.x * 128;
  f32x4 acc[4][4];
#pragma unroll
  for (int i = 0; i < 4; ++i)
#pragma unroll
    for (int j = 0; j < 4; ++j)
#pragma unroll
      for (int r = 0; r < 4; ++r) acc[i][j][r] = 0.f;
  gemm_mainloop(ctx, Wob, m0, n0, DM, Asm, Bsm, acc);
  const int lane = threadIdx.x & 63, wave = threadIdx.x >> 6;
  const int wr = wave >> 1, wc = wave & 1;
#pragma unroll
  for (int i = 0; i < 4; ++i)
#pragma unroll
    for (int j = 0; j < 4; ++j) {
      const int e = n0 + wc * 64 + j * 16 + (lane & 15);
      const float bval = bo[e];
#pragma unroll
      for (int r = 0; r < 4; ++r) {
        const int m = m0 + wr * 64 + i * 16 + ((lane >> 4) * 4) + r;
        out[(size_t)m * DM + e] = acc[i][j][r] + bval;
      }
    }
}

extern "C" void kernel_launch(void* const* d_in, const int* in_sizes, int n_in,
                              void* d_out, int out_size, void* d_ws, size_t ws_size,
                              hipStream_t stream) {
  const float* x  = (const float*)d_in[0];
  const float* Wq = (const float*)d_in[1];
  const float* bq = (const float*)d_in[2];
  const float* Wk = (const float*)d_in[3];
  const float* bk = (const float*)d_in[4];
  const float* Wv = (const float*)d_in[5];
  const float* bv = (const float*)d_in[6];
  const float* Wo = (const float*)d_in[7];
  const float* bo = (const float*)d_in[8];

  char* w = (char*)d_ws;
  u16* xb   = (u16*)(w);
  u16* wqb  = (u16*)(w + (8ull << 20));
  u16* wkb  = (u16*)(w + (10ull << 20));
  u16* wvb  = (u16*)(w + (12ull << 20));
  u16* wob  = (u16*)(w + (14ull << 20));
  u16* qb   = (u16*)(w + (16ull << 20));
  u16* kb   = (u16*)(w + (24ull << 20));
  u16* vtb  = (u16*)(w + (32ull << 20));
  u16* ctxb = (u16*)(w + (40ull << 20));
  float* ctab = (float*)(w + (48ull << 20));
  float* stab = ctab + T_SEQ * 32;

  cvt4<<<dim3((MTOK * DM) / 4 / 256), 256, 0, stream>>>(x, xb);
  cvtW<<<dim3((DM * DM) / 4 / 256, 4), 256, 0, stream>>>(Wq, Wk, Wv, Wo, wqb);
  rope_tab<<<dim3((T_SEQ * 32) / 256), 256, 0, stream>>>(ctab, stab);
  qkv_kernel<<<dim3(DM / 128, MTOK / 128, 3), 256, 0, stream>>>(
      xb, wqb, wkb, wvb, bq, bk, bv, ctab, stab, qb, kb, vtb);
  attn_kernel<<<dim3(64, 8), 256, 0, stream>>>(qb, kb, vtb, ctxb);
  oproj_kernel<<<dim3(DM / 128, MTOK / 128), 256, 0, stream>>>(ctxb, wob, bo, (float*)d_out);
}

// Round 3
// 116.131 us; speedup vs baseline: 1.1748x; 1.0623x over previous
//
#include <hip/hip_runtime.h>

// MHA: B=4, T=1024, D=1024, H=16, HD=64. Causal mask, interleaved RoPE.
// bf16 MFMA (16x16x32) everywhere, fp32 accumulate.
// R3: GEMM mainloop -> depth-2 counted-vmcnt pipeline (triple-buffered LDS,
// vmcnt(4) boundary waits, raw s_barrier), XOR-swizzled LDS reads via
// pre-swizzled global source, fused QKV GEMM (N=3072), merged prep kernel.

#define T_SEQ 1024
#define NH    16
#define HDIM  64
#define DM    1024
#define MTOK  4096   // B*T

typedef __attribute__((ext_vector_type(8))) short short8;
typedef __attribute__((ext_vector_type(4))) float f32x4;
typedef unsigned short u16;

__device__ __forceinline__ u16 f2bf(float f) {
  unsigned int u = __builtin_bit_cast(unsigned int, f);
  u += 0x7fffu + ((u >> 16) & 1u);
  return (u16)(u >> 16);
}

// async global->LDS, 16B per lane. LDS dest must be wave-uniform base + lane*16.
__device__ __forceinline__ void gll16(const void* g, void* l) {
  __builtin_amdgcn_global_load_lds(
      (const __attribute__((address_space(1))) unsigned int*)(unsigned long long)(g),
      (__attribute__((address_space(3))) unsigned int*)(unsigned int)(unsigned long long)(l),
      16, 0, 0);
}

// ---------------- prep: x->bf16, W->bf16 (fused qkv+o), rope tables ----------------
__global__ void prep_kernel(const float* __restrict__ x,
                            const float* __restrict__ Wq, const float* __restrict__ Wk,
                            const float* __restrict__ Wv, const float* __restrict__ Wo,
                            u16* __restrict__ xb, u16* __restrict__ wall,
                            float* __restrict__ ctab, float* __restrict__ stab) {
  const int bid = blockIdx.x, tid = threadIdx.x;
  if (bid < 8192) {
    const float* src;
    u16* dst;
    int i;
    if (bid < 4096) {
      src = x; dst = xb; i = bid * 256 + tid;
    } else {
      const int w = (bid - 4096) >> 10;
      src = w == 0 ? Wq : w == 1 ? Wk : w == 2 ? Wv : Wo;
      dst = wall + (size_t)w * (DM * DM);
      i = ((bid - 4096) & 1023) * 256 + tid;
    }
    float4 f = ((const float4*)src)[i];
    unsigned long long pk = (unsigned long long)f2bf(f.x)
                          | ((unsigned long long)f2bf(f.y) << 16)
                          | ((unsigned long long)f2bf(f.z) << 32)
                          | ((unsigned long long)f2bf(f.w) << 48);
    ((unsigned long long*)dst)[i] = pk;
  } else {
    const int idx = (bid - 8192) * 256 + tid;  // T*32
    const int t = idx >> 5, i = idx & 31;
    float inv = powf(10000.f, -(float)i * (1.0f / 32.0f));
    float f = (float)t * inv;
    ctab[idx] = cosf(f);
    stab[idx] = sinf(f);
  }
}

// ---------------- pipelined GEMM mainloop ----------------
// C[128x128] tile, A:[M][1024] bf16, Bw:[N][1024] bf16 (row = output col).
// Depth-2 pipeline: triple-buffered LDS, counted vmcnt(4) at tile boundary,
// raw s_barrier (no vmcnt0 drain). LDS chunk-swizzle: 16B chunk c of row r
// stored at position c ^ ((r>>1)&3)  (applied on global src, read with same XOR).
__device__ __forceinline__ void gemm_pipe(
    const u16* __restrict__ A, const u16* __restrict__ Bw,
    int m0, int n0, u16* As, u16* Bs, f32x4 acc[4][4]) {
  const int tid = threadIdx.x, lane = tid & 63, wave = tid >> 6;
  const int wr = wave >> 1, wc = wave & 1;
  const int swz = ((tid & 3) ^ ((tid >> 3) & 3)) * 8;
  const size_t Aofs = (size_t)(m0 + (tid >> 2)) * DM + swz;
  const size_t Bofs = (size_t)(n0 + (tid >> 2)) * DM + swz;
  const int ldst = tid * 8;  // u16 units
  const int NT = DM / 32;    // 32 K-steps

#define STAGE_T(t, b)                                                   \
  do {                                                                  \
    gll16(&A[Aofs + (t) * 32],         &As[(b) * 4096 + ldst]);         \
    gll16(&A[Aofs + 65536 + (t) * 32], &As[(b) * 4096 + 2048 + ldst]);  \
    gll16(&Bw[Bofs + (t) * 32],        &Bs[(b) * 4096 + ldst]);         \
    gll16(&Bw[Bofs + 65536 + (t) * 32], &Bs[(b) * 4096 + 2048 + ldst]); \
  } while (0)

  STAGE_T(0, 0);
  STAGE_T(1, 1);
  const int arow = (wr * 64 + (lane & 15)) * 32 + (((lane >> 4) ^ ((lane >> 1) & 3)) * 8);
  const int brow = (wc * 64 + (lane & 15)) * 32 + (((lane >> 4) ^ ((lane >> 1) & 3)) * 8);
  int cbuf = 0, sbuf = 2;
  for (int t = 0; t < NT; ++t) {
    if (t + 1 < NT) {
      asm volatile("s_waitcnt vmcnt(4)" ::: "memory");
    } else {
      asm volatile("s_waitcnt vmcnt(0)" ::: "memory");
    }
    asm volatile("s_barrier" ::: "memory");
    if (t + 2 < NT) STAGE_T(t + 2, sbuf);
    short8 af[4], bf[4];
#pragma unroll
    for (int i = 0; i < 4; ++i) {
      af[i] = *(const short8*)&As[cbuf * 4096 + arow + i * 512];
      bf[i] = *(const short8*)&Bs[cbuf * 4096 + brow + i * 512];
    }
#pragma unroll
    for (int i = 0; i < 4; ++i)
#pragma unroll
      for (int j = 0; j < 4; ++j)
        acc[i][j] = __builtin_amdgcn_mfma_f32_16x16x32_bf16(af[i], bf[j], acc[i][j], 0, 0, 0);
    asm volatile("s_waitcnt lgkmcnt(0)" ::: "memory");  // drain reads before next stage overwrites
    asm volatile("s_barrier" ::: "memory");
    cbuf = cbuf == 2 ? 0 : cbuf + 1;
    sbuf = sbuf == 2 ? 0 : sbuf + 1;
  }
#undef STAGE_T
}

// ---------------- fused QKV projection + bias + RoPE + layout ----------------
__global__ __launch_bounds__(256) void qkv_kernel(
    const u16* __restrict__ xb, const u16* __restrict__ wqkv,
    const float* __restrict__ bq, const float* __restrict__ bk, const float* __restrict__ bv,
    const float* __restrict__ ctab, const float* __restrict__ stab,
    u16* __restrict__ qbuf, u16* __restrict__ kbuf, u16* __restrict__ vt) {
  __shared__ __align__(16) u16 As[3 * 4096];
  __shared__ __align__(16) u16 Bs[3 * 4096];
  const int m0 = blockIdx.y * 128;
  const int n0 = blockIdx.x * 128;      // 0..2944 across fused Wq|Wk|Wv rows
  const int mode = n0 >> 10;
  const float* bias = mode == 0 ? bq : (mode == 1 ? bk : bv);
  f32x4 acc[4][4];
#pragma unroll
  for (int i = 0; i < 4; ++i)
#pragma unroll
    for (int j = 0; j < 4; ++j)
#pragma unroll
      for (int r = 0; r < 4; ++r) acc[i][j][r] = 0.f;
  gemm_pipe(xb, wqkv, m0, n0, As, Bs, acc);

  const int lane = threadIdx.x & 63, wave = threadIdx.x >> 6;
  const int wr = wave >> 1, wc = wave & 1;
#pragma unroll
  for (int i = 0; i < 4; ++i) {
#pragma unroll
    for (int j = 0; j < 4; ++j) {
      const int e = n0 + wc * 64 + j * 16 + (lane & 15);   // global fused col
      const float bval = bias[e & 1023];
      const int h = (e >> 6) & 15, hd = e & 63;
#pragma unroll
      for (int r = 0; r < 4; ++r) {
        const int m = m0 + wr * 64 + i * 16 + ((lane >> 4) * 4) + r;
        const int b = m >> 10, t = m & 1023;
        float v = acc[i][j][r] + bval;
        if (mode < 2) {
          float p = __shfl_xor(v, 1);  // partner within the (even,odd) pair
          const int fi = hd >> 1;
          const float cc = ctab[t * 32 + fi], ss = stab[t * 32 + fi];
          v = (hd & 1) ? (v * cc + p * ss) : (v * cc - p * ss);
          u16* dst = mode == 0 ? qbuf : kbuf;
          dst[(((size_t)(b * NH + h) * T_SEQ + t) << 6) + hd] = f2bf(v);
        } else {
          vt[(((size_t)(b * NH + h) * HDIM + hd) << 10) + t] = f2bf(v);
        }
      }
    }
  }
}

// ---------------- flash attention ----------------
// Block = (b,h) x {q-tile qt, q-tile 15-qt}: uniform 17 KV tiles per block.
// 4 waves x 16 q-rows. K/V double-buffered + XOR-swizzled LDS.
__global__ __launch_bounds__(256) void attn_kernel(
    const u16* __restrict__ qbuf, const u16* __restrict__ kbuf,
    const u16* __restrict__ vtb, u16* __restrict__ ctx) {
  __shared__ __align__(16) u16 Ks[2][64 * 64];   // [kv][hd] swizzled
  __shared__ __align__(16) u16 Vs[2][64 * 64];   // [hd][kv] swizzled (V^T tile)
  __shared__ __align__(16) u16 Psm[4][16 * 64];  // per-wave P, swizzled
  const int bh = blockIdx.x;
  const int b = bh >> 4, h = bh & 15;
  const int tid = threadIdx.x, lane = tid & 63, wave = tid >> 6;
  const u16* Qp = qbuf + (size_t)bh * T_SEQ * HDIM;
  const u16* Kp = kbuf + (size_t)bh * T_SEQ * HDIM;
  const u16* Vp = vtb + (size_t)bh * HDIM * T_SEQ;
  u16* Pw = &Psm[wave][0];

  const int srow = tid >> 3;                     // staging row (0..31, +32 for c=1)
  const int schx = ((tid & 7) ^ (srow & 7)) * 8; // pre-swizzled chunk (u16 offset)
  const int lx = lane & 7;                       // row&7 for all read rows below

#define STG(kvt, bb)                                                            \
  do {                                                                          \
    _Pragma("unroll") for (int c = 0; c < 2; ++c) {                             \
      const int rr = c * 32 + srow;                                             \
      gll16(&Kp[(kvt) * 4096 + rr * 64 + schx], &Ks[bb][c * 2048 + tid * 8]);   \
      gll16(&Vp[(size_t)rr * T_SEQ + (kvt) * 64 + schx], &Vs[bb][c * 2048 + tid * 8]); \
    }                                                                           \
  } while (0)

  for (int phase = 0; phase < 2; ++phase) {
    const int qt = phase ? (15 - (int)blockIdx.y) : (int)blockIdx.y;
    const int q0 = qt * 64;
    const int nkv = qt + 1;
    const int qrow = q0 + wave * 16 + (lane & 15);
    const short8 qf0 = *(const short8*)&Qp[qrow * 64 + ((lane >> 4) * 8)];
    const short8 qf1 = *(const short8*)&Qp[qrow * 64 + 32 + ((lane >> 4) * 8)];

    f32x4 acc_o[4];
    float m_r[4], l_r[4];
#pragma unroll
    for (int i = 0; i < 4; ++i) {
#pragma unroll
      for (int r = 0; r < 4; ++r) acc_o[i][r] = 0.f;
      m_r[i] = -__builtin_inff();
      l_r[i] = 0.f;
    }

    __syncthreads();   // previous phase's readers done before restaging buf0
    STG(0, 0);
    int cur = 0;

    for (int kvt = 0; kvt < nkv; ++kvt) {
      __syncthreads();                       // buf[cur] staged (vmcnt drained)
      if (kvt + 1 < nkv) STG(kvt + 1, cur ^ 1);

      // S = Q K^T (16x64 per wave)
      f32x4 sacc[4];
#pragma unroll
      for (int cb = 0; cb < 4; ++cb) {
#pragma unroll
        for (int r = 0; r < 4; ++r) sacc[cb][r] = 0.f;
        const int krow = cb * 16 + (lane & 15);
        const short8 kf0 = *(const short8*)&Ks[cur][krow * 64 + (((lane >> 4) ^ lx) * 8)];
        const short8 kf1 = *(const short8*)&Ks[cur][krow * 64 + (((4 + (lane >> 4)) ^ lx) * 8)];
        sacc[cb] = __builtin_amdgcn_mfma_f32_16x16x32_bf16(qf0, kf0, sacc[cb], 0, 0, 0);
        sacc[cb] = __builtin_amdgcn_mfma_f32_16x16x32_bf16(qf1, kf1, sacc[cb], 0, 0, 0);
      }
      // scale + causal mask
      const int trow_base = q0 + wave * 16 + ((lane >> 4) * 4);
#pragma unroll
      for (int cb = 0; cb < 4; ++cb) {
        const int scol = kvt * 64 + cb * 16 + (lane & 15);
#pragma unroll
        for (int r = 0; r < 4; ++r) {
          float sv = sacc[cb][r] * 0.125f;
          sacc[cb][r] = (scol > trow_base + r) ? -__builtin_inff() : sv;
        }
      }
      // online softmax (rows live across 16 lanes x 4 col-blocks)
      float mt[4];
#pragma unroll
      for (int r = 0; r < 4; ++r)
        mt[r] = fmaxf(fmaxf(sacc[0][r], sacc[1][r]), fmaxf(sacc[2][r], sacc[3][r]));
#pragma unroll
      for (int off = 1; off < 16; off <<= 1)
#pragma unroll
        for (int r = 0; r < 4; ++r) mt[r] = fmaxf(mt[r], __shfl_xor(mt[r], off));
      float sf[4], lt[4];
#pragma unroll
      for (int r = 0; r < 4; ++r) {
        const float mn = fmaxf(m_r[r], mt[r]);
        sf[r] = __expf(m_r[r] - mn);
        m_r[r] = mn;
        lt[r] = 0.f;
      }
#pragma unroll
      for (int cb = 0; cb < 4; ++cb)
#pragma unroll
        for (int r = 0; r < 4; ++r) {
          const float p = __expf(sacc[cb][r] - m_r[r]);
          sacc[cb][r] = p;
          lt[r] += p;
        }
#pragma unroll
      for (int off = 1; off < 16; off <<= 1)
#pragma unroll
        for (int r = 0; r < 4; ++r) lt[r] += __shfl_xor(lt[r], off);
#pragma unroll
      for (int r = 0; r < 4; ++r) l_r[r] = l_r[r] * sf[r] + lt[r];
#pragma unroll
      for (int hb = 0; hb < 4; ++hb)
#pragma unroll
        for (int r = 0; r < 4; ++r) acc_o[hb][r] *= sf[r];

      // P (C-layout) -> LDS (swizzled) -> A-layout
#pragma unroll
      for (int cb = 0; cb < 4; ++cb)
#pragma unroll
        for (int r = 0; r < 4; ++r) {
          const int prow = (lane >> 4) * 4 + r;
          Pw[prow * 64 + ((cb * 16 + (lane & 15)) ^ ((prow & 7) << 3))] = f2bf(sacc[cb][r]);
        }

      // O += P V
      const int prr = lane & 15;
#pragma unroll
      for (int kc = 0; kc < 2; ++kc) {
        const short8 pf = *(const short8*)&Pw[prr * 64 + (((kc * 4 + (lane >> 4)) ^ lx) * 8)];
#pragma unroll
        for (int hb = 0; hb < 4; ++hb) {
          const int vrow = hb * 16 + (lane & 15);
          const short8 vf = *(const short8*)&Vs[cur][vrow * 64 + (((kc * 4 + (lane >> 4)) ^ lx) * 8)];
          acc_o[hb] = __builtin_amdgcn_mfma_f32_16x16x32_bf16(pf, vf, acc_o[hb], 0, 0, 0);
        }
      }
      cur ^= 1;
    }

    // epilogue: ctx[b][t][h][hd] bf16
#pragma unroll
    for (int hb = 0; hb < 4; ++hb) {
      const int hd = hb * 16 + (lane & 15);
#pragma unroll
      for (int r = 0; r < 4; ++r) {
        const int t = q0 + wave * 16 + ((lane >> 4) * 4) + r;
        const float v = acc_o[hb][r] / l_r[r];
        ctx[((size_t)(b * T_SEQ + t) * NH + h) * HDIM + hd] = f2bf(v);
      }
    }
  }
#undef STG
}

// ---------------- output projection -> fp32 d_out ----------------
__global__ __launch_bounds__(256) void oproj_kernel(
    const u16* __restrict__ ctx, const u16* __restrict__ Wob,
    const float* __restrict__ bo, float* __restrict__ out) {
  __shared__ __align__(16) u16 As[3 * 4096];
  __shared__ __align__(16) u16 Bs[3 * 4096];
  const int m0 = blockIdx.y * 128, n0 = blockIdx.x * 128;
  f32x4 acc[4][4];
#pragma unroll
  for (int i = 0; i < 4; ++i)
#pragma unroll
    for (int j = 0; j < 4; ++j)
#pragma unroll
      for (int r = 0; r < 4; ++r) acc[i][j][r] = 0.f;
  gemm_pipe(ctx, Wob, m0, n0, As, Bs, acc);
  const int lane = threadIdx.x & 63, wave = threadIdx.x >> 6;
  const int wr = wave >> 1, wc = wave & 1;
#pragma unroll
  for (int i = 0; i < 4; ++i)
#pragma unroll
    for (int j = 0; j < 4; ++j) {
      const int e = n0 + wc * 64 + j * 16 + (lane & 15);
      const float bval = bo[e];
#pragma unroll
      for (int r = 0; r < 4; ++r) {
        const int m = m0 + wr * 64 + i * 16 + ((lane >> 4) * 4) + r;
        out[(size_t)m * DM + e] = acc[i][j][r] + bval;
      }
    }
}

extern "C" void kernel_launch(void* const* d_in, const int* in_sizes, int n_in,
                              void* d_out, int out_size, void* d_ws, size_t ws_size,
                              hipStream_t stream) {
  const float* x  = (const float*)d_in[0];
  const float* Wq = (const float*)d_in[1];
  const float* bq = (const float*)d_in[2];
  const float* Wk = (const float*)d_in[3];
  const float* bk = (const float*)d_in[4];
  const float* Wv = (const float*)d_in[5];
  const float* bv = (const float*)d_in[6];
  const float* Wo = (const float*)d_in[7];
  const float* bo = (const float*)d_in[8];

  char* w = (char*)d_ws;
  u16* xb   = (u16*)(w);
  u16* wall = (u16*)(w + (8ull << 20));   // Wq|Wk|Wv|Wo bf16, 2MB each
  u16* wob  = (u16*)(w + (14ull << 20));
  u16* qb   = (u16*)(w + (16ull << 20));
  u16* kb   = (u16*)(w + (24ull << 20));
  u16* vtb  = (u16*)(w + (32ull << 20));
  u16* ctxb = (u16*)(w + (40ull << 20));
  float* ctab = (float*)(w + (48ull << 20));
  float* stab = ctab + T_SEQ * 32;

  prep_kernel<<<dim3(8192 + 128), 256, 0, stream>>>(x, Wq, Wk, Wv, Wo, xb, wall, ctab, stab);
  qkv_kernel<<<dim3(3 * DM / 128, MTOK / 128), 256, 0, stream>>>(
      xb, wall, bq, bk, bv, ctab, stab, qb, kb, vtb);
  attn_kernel<<<dim3(64, 8), 256, 0, stream>>>(qb, kb, vtb, ctxb);
  oproj_kernel<<<dim3(DM / 128, MTOK / 128), 256, 0, stream>>>(ctxb, wob, bo, (float*)d_out);
}

// Round 4
// 109.948 us; speedup vs baseline: 1.2408x; 1.0562x over previous
//
#include <hip/hip_runtime.h>

// MHA: B=4, T=1024, D=1024, H=16, HD=64. Causal mask, interleaved RoPE.
// bf16 MFMA (16x16x32) everywhere, fp32 accumulate.
// R4: GEMMs -> single-barrier-per-iter pipeline (stage-first, one
// __syncthreads per K-step = the guide's minimum-2-phase recipe), BK=64,
// qkv tile 128x192 (grid 512 = exactly 2 blocks/CU), oproj 64x128 (512
// blocks). XOR-swizzled LDS via pre-swizzled global source.

#define T_SEQ 1024
#define NH    16
#define HDIM  64
#define DM    1024
#define MTOK  4096   // B*T

typedef __attribute__((ext_vector_type(8))) short short8;
typedef __attribute__((ext_vector_type(4))) float f32x4;
typedef unsigned short u16;

__device__ __forceinline__ u16 f2bf(float f) {
  unsigned int u = __builtin_bit_cast(unsigned int, f);
  u += 0x7fffu + ((u >> 16) & 1u);
  return (u16)(u >> 16);
}

// async global->LDS, 16B per lane. LDS dest must be wave-uniform base + lane*16.
__device__ __forceinline__ void gll16(const void* g, void* l) {
  __builtin_amdgcn_global_load_lds(
      (const __attribute__((address_space(1))) unsigned int*)(unsigned long long)(g),
      (__attribute__((address_space(3))) unsigned int*)(unsigned int)(unsigned long long)(l),
      16, 0, 0);
}

// ---------------- prep: x->bf16, W->bf16 (fused qkv+o), rope tables ----------------
__global__ void prep_kernel(const float* __restrict__ x,
                            const float* __restrict__ Wq, const float* __restrict__ Wk,
                            const float* __restrict__ Wv, const float* __restrict__ Wo,
                            u16* __restrict__ xb, u16* __restrict__ wall,
                            float* __restrict__ ctab, float* __restrict__ stab) {
  const int bid = blockIdx.x, tid = threadIdx.x;
  if (bid < 8192) {
    const float* src;
    u16* dst;
    int i;
    if (bid < 4096) {
      src = x; dst = xb; i = bid * 256 + tid;
    } else {
      const int w = (bid - 4096) >> 10;
      src = w == 0 ? Wq : w == 1 ? Wk : w == 2 ? Wv : Wo;
      dst = wall + (size_t)w * (DM * DM);
      i = ((bid - 4096) & 1023) * 256 + tid;
    }
    float4 f = ((const float4*)src)[i];
    unsigned long long pk = (unsigned long long)f2bf(f.x)
                          | ((unsigned long long)f2bf(f.y) << 16)
                          | ((unsigned long long)f2bf(f.z) << 32)
                          | ((unsigned long long)f2bf(f.w) << 48);
    ((unsigned long long*)dst)[i] = pk;
  } else {
    const int idx = (bid - 8192) * 256 + tid;  // T*32
    const int t = idx >> 5, i = idx & 31;
    float inv = powf(10000.f, -(float)i * (1.0f / 32.0f));
    float f = (float)t * inv;
    ctab[idx] = cosf(f);
    stab[idx] = sinf(f);
  }
}

// ---------------- single-barrier pipelined GEMM mainloop ----------------
// A:[M][1024] bf16, Bw:[N][1024] bf16 (row = output col). BK=64, NT=16.
// 4 waves in 2x2 grid: per-wave output (BM/2) x (BN/2), MI x NJ 16x16 frags.
// LDS layout: row-major [rows][64], 16B chunk c of row r stored at chunk
// position c ^ (r&7) (inverse-swizzle applied to GLOBAL source; reads use
// the same XOR). One __syncthreads per iter (drains vmcnt+lgkm = the fence
// both the staged buffer and the WAR on buf^1 need).
template<int BM, int BN, int AI, int BI, int MI, int NJ>
__device__ __forceinline__ void gemm_pipe2(
    const u16* __restrict__ A, const u16* __restrict__ Bw,
    int m0, int n0, u16* As, u16* Bs, f32x4 acc[MI][NJ]) {
  const int tid = threadIdx.x, lane = tid & 63, wave = tid >> 6;
  const int wr = wave >> 1, wc = wave & 1;
  const int srcswz = ((lane & 7) ^ (lane >> 3)) * 8;  // u16 offset within K-slice
  const int NT = DM / 64;

#define STAGE2(t, b)                                                         \
  do {                                                                       \
    _Pragma("unroll") for (int i = 0; i < AI; ++i) {                         \
      const int q = (wave * AI + i) * 64 + lane;                             \
      gll16(&A[(size_t)(m0 + (q >> 3)) * DM + (t) * 64 + srcswz],            \
            &As[(b) * BM * 64 + q * 8]);                                     \
    }                                                                        \
    _Pragma("unroll") for (int i = 0; i < BI; ++i) {                         \
      const int q = (wave * BI + i) * 64 + lane;                             \
      gll16(&Bw[(size_t)(n0 + (q >> 3)) * DM + (t) * 64 + srcswz],           \
            &Bs[(b) * BN * 64 + q * 8]);                                     \
    }                                                                        \
  } while (0)

  STAGE2(0, 0);
  __syncthreads();
  int buf = 0;
  const int arow0 = wr * (BM / 2) + (lane & 15);
  const int brow0 = wc * (BN / 2) + (lane & 15);
  const int c0 = (((lane >> 4)) ^ (lane & 7)) * 8;      // kk=0 chunk (XOR row&7 = lane&7)
  const int c1 = ((4 + (lane >> 4)) ^ (lane & 7)) * 8;  // kk=1 chunk
  for (int t = 0; t < NT; ++t) {
    if (t + 1 < NT) STAGE2(t + 1, buf ^ 1);
    short8 af[MI][2], bf[NJ][2];
#pragma unroll
    for (int i = 0; i < MI; ++i) {
      const int r = buf * BM * 64 + (arow0 + i * 16) * 64;
      af[i][0] = *(const short8*)&As[r + c0];
      af[i][1] = *(const short8*)&As[r + c1];
    }
#pragma unroll
    for (int j = 0; j < NJ; ++j) {
      const int r = buf * BN * 64 + (brow0 + j * 16) * 64;
      bf[j][0] = *(const short8*)&Bs[r + c0];
      bf[j][1] = *(const short8*)&Bs[r + c1];
    }
#pragma unroll
    for (int i = 0; i < MI; ++i)
#pragma unroll
      for (int j = 0; j < NJ; ++j) {
        acc[i][j] = __builtin_amdgcn_mfma_f32_16x16x32_bf16(af[i][0], bf[j][0], acc[i][j], 0, 0, 0);
        acc[i][j] = __builtin_amdgcn_mfma_f32_16x16x32_bf16(af[i][1], bf[j][1], acc[i][j], 0, 0, 0);
      }
    __syncthreads();
    buf ^= 1;
  }
#undef STAGE2
}

// ---------------- fused QKV projection + bias + RoPE + layout ----------------
// Tile 128x192, grid (3072/192=16) x (4096/128=32) = 512 blocks = 2/CU.
__global__ __launch_bounds__(256, 2) void qkv_kernel(
    const u16* __restrict__ xb, const u16* __restrict__ wqkv,
    const float* __restrict__ bq, const float* __restrict__ bk, const float* __restrict__ bv,
    const float* __restrict__ ctab, const float* __restrict__ stab,
    u16* __restrict__ qbuf, u16* __restrict__ kbuf, u16* __restrict__ vt) {
  __shared__ __align__(16) u16 As[2 * 128 * 64];   // 32 KB
  __shared__ __align__(16) u16 Bs[2 * 192 * 64];   // 48 KB
  const int m0 = blockIdx.y * 128;
  const int n0 = blockIdx.x * 192;      // fused col across Wq|Wk|Wv
  f32x4 acc[4][6];
#pragma unroll
  for (int i = 0; i < 4; ++i)
#pragma unroll
    for (int j = 0; j < 6; ++j)
#pragma unroll
      for (int r = 0; r < 4; ++r) acc[i][j][r] = 0.f;
  gemm_pipe2<128, 192, 4, 6, 4, 6>(xb, wqkv, m0, n0, As, Bs, acc);

  const int lane = threadIdx.x & 63, wave = threadIdx.x >> 6;
  const int wr = wave >> 1, wc = wave & 1;
#pragma unroll
  for (int i = 0; i < 4; ++i) {
#pragma unroll
    for (int j = 0; j < 6; ++j) {
      const int e = n0 + wc * 96 + j * 16 + (lane & 15);   // global fused col
      const int mode = e >> 10;                             // 0=q 1=k 2=v (uniform per j-block)
      const float* bias = mode == 0 ? bq : (mode == 1 ? bk : bv);
      const float bval = bias[e & 1023];
      const int h = (e >> 6) & 15, hd = e & 63;
#pragma unroll
      for (int r = 0; r < 4; ++r) {
        const int m = m0 + wr * 64 + i * 16 + ((lane >> 4) * 4) + r;
        const int b = m >> 10, t = m & 1023;
        float v = acc[i][j][r] + bval;
        if (mode < 2) {
          float p = __shfl_xor(v, 1);  // partner within the (even,odd) pair
          const int fi = hd >> 1;
          const float cc = ctab[t * 32 + fi], ss = stab[t * 32 + fi];
          v = (hd & 1) ? (v * cc + p * ss) : (v * cc - p * ss);
          u16* dst = mode == 0 ? qbuf : kbuf;
          dst[(((size_t)(b * NH + h) * T_SEQ + t) << 6) + hd] = f2bf(v);
        } else {
          vt[(((size_t)(b * NH + h) * HDIM + hd) << 10) + t] = f2bf(v);
        }
      }
    }
  }
}

// ---------------- flash attention (unchanged from R3) ----------------
__global__ __launch_bounds__(256) void attn_kernel(
    const u16* __restrict__ qbuf, const u16* __restrict__ kbuf,
    const u16* __restrict__ vtb, u16* __restrict__ ctx) {
  __shared__ __align__(16) u16 Ks[2][64 * 64];   // [kv][hd] swizzled
  __shared__ __align__(16) u16 Vs[2][64 * 64];   // [hd][kv] swizzled (V^T tile)
  __shared__ __align__(16) u16 Psm[4][16 * 64];  // per-wave P, swizzled
  const int bh = blockIdx.x;
  const int b = bh >> 4, h = bh & 15;
  const int tid = threadIdx.x, lane = tid & 63, wave = tid >> 6;
  const u16* Qp = qbuf + (size_t)bh * T_SEQ * HDIM;
  const u16* Kp = kbuf + (size_t)bh * T_SEQ * HDIM;
  const u16* Vp = vtb + (size_t)bh * HDIM * T_SEQ;
  u16* Pw = &Psm[wave][0];

  const int srow = tid >> 3;                     // staging row (0..31, +32 for c=1)
  const int schx = ((tid & 7) ^ (srow & 7)) * 8; // pre-swizzled chunk (u16 offset)
  const int lx = lane & 7;                       // row&7 for all read rows below

#define STG(kvt, bb)                                                            \
  do {                                                                          \
    _Pragma("unroll") for (int c = 0; c < 2; ++c) {                             \
      const int rr = c * 32 + srow;                                             \
      gll16(&Kp[(kvt) * 4096 + rr * 64 + schx], &Ks[bb][c * 2048 + tid * 8]);   \
      gll16(&Vp[(size_t)rr * T_SEQ + (kvt) * 64 + schx], &Vs[bb][c * 2048 + tid * 8]); \
    }                                                                           \
  } while (0)

  for (int phase = 0; phase < 2; ++phase) {
    const int qt = phase ? (15 - (int)blockIdx.y) : (int)blockIdx.y;
    const int q0 = qt * 64;
    const int nkv = qt + 1;
    const int qrow = q0 + wave * 16 + (lane & 15);
    const short8 qf0 = *(const short8*)&Qp[qrow * 64 + ((lane >> 4) * 8)];
    const short8 qf1 = *(const short8*)&Qp[qrow * 64 + 32 + ((lane >> 4) * 8)];

    f32x4 acc_o[4];
    float m_r[4], l_r[4];
#pragma unroll
    for (int i = 0; i < 4; ++i) {
#pragma unroll
      for (int r = 0; r < 4; ++r) acc_o[i][r] = 0.f;
      m_r[i] = -__builtin_inff();
      l_r[i] = 0.f;
    }

    __syncthreads();   // previous phase's readers done before restaging buf0
    STG(0, 0);
    int cur = 0;

    for (int kvt = 0; kvt < nkv; ++kvt) {
      __syncthreads();                       // buf[cur] staged (vmcnt drained)
      if (kvt + 1 < nkv) STG(kvt + 1, cur ^ 1);

      // S = Q K^T (16x64 per wave)
      f32x4 sacc[4];
#pragma unroll
      for (int cb = 0; cb < 4; ++cb) {
#pragma unroll
        for (int r = 0; r < 4; ++r) sacc[cb][r] = 0.f;
        const int krow = cb * 16 + (lane & 15);
        const short8 kf0 = *(const short8*)&Ks[cur][krow * 64 + (((lane >> 4) ^ lx) * 8)];
        const short8 kf1 = *(const short8*)&Ks[cur][krow * 64 + (((4 + (lane >> 4)) ^ lx) * 8)];
        sacc[cb] = __builtin_amdgcn_mfma_f32_16x16x32_bf16(qf0, kf0, sacc[cb], 0, 0, 0);
        sacc[cb] = __builtin_amdgcn_mfma_f32_16x16x32_bf16(qf1, kf1, sacc[cb], 0, 0, 0);
      }
      // scale + causal mask
      const int trow_base = q0 + wave * 16 + ((lane >> 4) * 4);
#pragma unroll
      for (int cb = 0; cb < 4; ++cb) {
        const int scol = kvt * 64 + cb * 16 + (lane & 15);
#pragma unroll
        for (int r = 0; r < 4; ++r) {
          float sv = sacc[cb][r] * 0.125f;
          sacc[cb][r] = (scol > trow_base + r) ? -__builtin_inff() : sv;
        }
      }
      // online softmax (rows live across 16 lanes x 4 col-blocks)
      float mt[4];
#pragma unroll
      for (int r = 0; r < 4; ++r)
        mt[r] = fmaxf(fmaxf(sacc[0][r], sacc[1][r]), fmaxf(sacc[2][r], sacc[3][r]));
#pragma unroll
      for (int off = 1; off < 16; off <<= 1)
#pragma unroll
        for (int r = 0; r < 4; ++r) mt[r] = fmaxf(mt[r], __shfl_xor(mt[r], off));
      float sf[4], lt[4];
#pragma unroll
      for (int r = 0; r < 4; ++r) {
        const float mn = fmaxf(m_r[r], mt[r]);
        sf[r] = __expf(m_r[r] - mn);
        m_r[r] = mn;
        lt[r] = 0.f;
      }
#pragma unroll
      for (int cb = 0; cb < 4; ++cb)
#pragma unroll
        for (int r = 0; r < 4; ++r) {
          const float p = __expf(sacc[cb][r] - m_r[r]);
          sacc[cb][r] = p;
          lt[r] += p;
        }
#pragma unroll
      for (int off = 1; off < 16; off <<= 1)
#pragma unroll
        for (int r = 0; r < 4; ++r) lt[r] += __shfl_xor(lt[r], off);
#pragma unroll
      for (int r = 0; r < 4; ++r) l_r[r] = l_r[r] * sf[r] + lt[r];
#pragma unroll
      for (int hb = 0; hb < 4; ++hb)
#pragma unroll
        for (int r = 0; r < 4; ++r) acc_o[hb][r] *= sf[r];

      // P (C-layout) -> LDS (swizzled) -> A-layout
#pragma unroll
      for (int cb = 0; cb < 4; ++cb)
#pragma unroll
        for (int r = 0; r < 4; ++r) {
          const int prow = (lane >> 4) * 4 + r;
          Pw[prow * 64 + ((cb * 16 + (lane & 15)) ^ ((prow & 7) << 3))] = f2bf(sacc[cb][r]);
        }

      // O += P V
      const int prr = lane & 15;
#pragma unroll
      for (int kc = 0; kc < 2; ++kc) {
        const short8 pf = *(const short8*)&Pw[prr * 64 + (((kc * 4 + (lane >> 4)) ^ lx) * 8)];
#pragma unroll
        for (int hb = 0; hb < 4; ++hb) {
          const int vrow = hb * 16 + (lane & 15);
          const short8 vf = *(const short8*)&Vs[cur][vrow * 64 + (((kc * 4 + (lane >> 4)) ^ lx) * 8)];
          acc_o[hb] = __builtin_amdgcn_mfma_f32_16x16x32_bf16(pf, vf, acc_o[hb], 0, 0, 0);
        }
      }
      cur ^= 1;
    }

    // epilogue: ctx[b][t][h][hd] bf16
#pragma unroll
    for (int hb = 0; hb < 4; ++hb) {
      const int hd = hb * 16 + (lane & 15);
#pragma unroll
      for (int r = 0; r < 4; ++r) {
        const int t = q0 + wave * 16 + ((lane >> 4) * 4) + r;
        const float v = acc_o[hb][r] / l_r[r];
        ctx[((size_t)(b * T_SEQ + t) * NH + h) * HDIM + hd] = f2bf(v);
      }
    }
  }
#undef STG
}

// ---------------- output projection -> fp32 d_out ----------------
// Tile 64x128, grid (1024/128=8) x (4096/64=64) = 512 blocks.
__global__ __launch_bounds__(256, 2) void oproj_kernel(
    const u16* __restrict__ ctx, const u16* __restrict__ Wob,
    const float* __restrict__ bo, float* __restrict__ out) {
  __shared__ __align__(16) u16 As[2 * 64 * 64];    // 16 KB
  __shared__ __align__(16) u16 Bs[2 * 128 * 64];   // 32 KB
  const int m0 = blockIdx.y * 64, n0 = blockIdx.x * 128;
  f32x4 acc[2][4];
#pragma unroll
  for (int i = 0; i < 2; ++i)
#pragma unroll
    for (int j = 0; j < 4; ++j)
#pragma unroll
      for (int r = 0; r < 4; ++r) acc[i][j][r] = 0.f;
  gemm_pipe2<64, 128, 2, 4, 2, 4>(ctx, Wob, m0, n0, As, Bs, acc);
  const int lane = threadIdx.x & 63, wave = threadIdx.x >> 6;
  const int wr = wave >> 1, wc = wave & 1;
#pragma unroll
  for (int i = 0; i < 2; ++i)
#pragma unroll
    for (int j = 0; j < 4; ++j) {
      const int e = n0 + wc * 64 + j * 16 + (lane & 15);
      const float bval = bo[e];
#pragma unroll
      for (int r = 0; r < 4; ++r) {
        const int m = m0 + wr * 32 + i * 16 + ((lane >> 4) * 4) + r;
        out[(size_t)m * DM + e] = acc[i][j][r] + bval;
      }
    }
}

extern "C" void kernel_launch(void* const* d_in, const int* in_sizes, int n_in,
                              void* d_out, int out_size, void* d_ws, size_t ws_size,
                              hipStream_t stream) {
  const float* x  = (const float*)d_in[0];
  const float* Wq = (const float*)d_in[1];
  const float* bq = (const float*)d_in[2];
  const float* Wk = (const float*)d_in[3];
  const float* bk = (const float*)d_in[4];
  const float* Wv = (const float*)d_in[5];
  const float* bv = (const float*)d_in[6];
  const float* Wo = (const float*)d_in[7];
  const float* bo = (const float*)d_in[8];

  char* w = (char*)d_ws;
  u16* xb   = (u16*)(w);
  u16* wall = (u16*)(w + (8ull << 20));   // Wq|Wk|Wv|Wo bf16, 2MB each
  u16* wob  = (u16*)(w + (14ull << 20));
  u16* qb   = (u16*)(w + (16ull << 20));
  u16* kb   = (u16*)(w + (24ull << 20));
  u16* vtb  = (u16*)(w + (32ull << 20));
  u16* ctxb = (u16*)(w + (40ull << 20));
  float* ctab = (float*)(w + (48ull << 20));
  float* stab = ctab + T_SEQ * 32;

  prep_kernel<<<dim3(8192 + 128), 256, 0, stream>>>(x, Wq, Wk, Wv, Wo, xb, wall, ctab, stab);
  qkv_kernel<<<dim3(3 * DM / 192, MTOK / 128), 256, 0, stream>>>(
      xb, wall, bq, bk, bv, ctab, stab, qb, kb, vtb);
  attn_kernel<<<dim3(64, 8), 256, 0, stream>>>(qb, kb, vtb, ctxb);
  oproj_kernel<<<dim3(DM / 128, MTOK / 64), 256, 0, stream>>>(ctxb, wob, bo, (float*)d_out);
}